// Round 7
// baseline (257.218 us; speedup 1.0000x reference)
//
#include <hip/hip_runtime.h>
#include <stdint.h>

#define T_STEPS 256
#define BATCH   2048
#define ISZ     11
#define HID     64
#define PHOR    12
#define BPB     8     // batches per block (256 blocks = 1/CU)
#define BPC     4     // batches per chain (2 chains per block)

typedef __attribute__((ext_vector_type(8))) short short8;
typedef __attribute__((ext_vector_type(4))) float f32x4;

union S8U { short8 s; uint32_t u[4]; };

__device__ __forceinline__ uint32_t cvt_pk_bf16(float lo, float hi) {
  uint32_t r;
  asm("v_cvt_pk_bf16_f32 %0, %1, %2" : "=v"(r) : "v"(lo), "v"(hi));
  return r;
}
// sigmoid with pre-scaled input: z = -log2(e)*v  ->  sigm = 1/(1+2^z)
__device__ __forceinline__ float sigm_z(float z) {
  return __builtin_amdgcn_rcpf(1.0f + __builtin_amdgcn_exp2f(z));
}
// gfx950: D0 odd 16-groups <-> D1 even 16-groups. After: a=[a0,b0,a2,b2]
__device__ __forceinline__ void plswap16(float &a, float &b) {
  asm("v_permlane16_swap_b32 %0, %1" : "+v"(a), "+v"(b));
}
// D0.hi <-> D1.lo. After: a=[a.lo, b.lo]
__device__ __forceinline__ void plswap32(float &a, float &b) {
  asm("v_permlane32_swap_b32 %0, %1" : "+v"(a), "+v"(b));
}
// Barrier draining LDS only — global loads stay in flight (no vmcnt(0)).
__device__ __forceinline__ void lds_barrier() {
  asm volatile("s_waitcnt lgkmcnt(0)" ::: "memory");
  __builtin_amdgcn_s_barrier();
  asm volatile("" ::: "memory");
}

// One block = 4 waves, TWO independent 4-batch chains (P,Q) at half-step
// offset in one instruction stream. Phase1: ds_read+MFMA for P overlaps
// cell of Q; phase2 mirrors. Gate redistribution (rows 0-3 in lanes 0-15,
// regs 0-3 -> one cell per lane: lane = batch*16 + unit%16) is pure VALU
// via permlane16_swap + permlane32_swap, so it never waits on lgkmcnt.
__global__ __launch_bounds__(256, 1)
void lstm_fused(const float* __restrict__ x, const float* __restrict__ y,
                const float* __restrict__ Wih_e, const float* __restrict__ Whh_e,
                const float* __restrict__ b_e,
                const float* __restrict__ Wih_d, const float* __restrict__ Whh_d,
                const float* __restrict__ b_d,
                const float* __restrict__ Wfc, const float* __restrict__ bfc,
                float* __restrict__ out)
{
  const int tid  = threadIdx.x;
  const int lane = tid & 63;
  const int wv   = tid >> 6;      // 0..3
  const int lc   = lane & 15;     // A-row (batch) / D-col (unit) within tile
  const int lg   = lane >> 4;     // after redistribution: batch index 0..3
  const int b0P  = blockIdx.x * BPB;
  const int b0Q  = b0P + BPC;
  const int j    = 16*wv + lc;    // hidden unit this lane owns

  // h per chain: [chain][buf][16 rows (4 real)][64 units] bf16, XOR-swizzled
  // 16B granules: elem (b,u) at b*64 + ((u>>3)^(b&7))*8 + (u&7).
  // Encoder uses buf0 only (read/write barrier-separated); decoder alternates.
  __shared__ __align__(16) unsigned short hsm[2][2][16][64];
  __shared__ float red[2][2][4][4];   // [chain][pb][wv][batch]
  unsigned short* hP = &hsm[0][0][0][0];
  unsigned short* hQ = &hsm[1][0][0][0];
  for (int idx = tid; idx < 2*2*16*64; idx += 256) (&hsm[0][0][0][0])[idx] = 0;

  const int rof0 = lc*64 + ((lg     ^ (lc&7)))*8;
  const int rof1 = lc*64 + (((4+lg) ^ (lc&7)))*8;
  const int wof  = lg*64 + (((j>>3) ^ (lg&7))*8) + (j&7);   // batch=lg rows 0-3

  // gate scales: PyTorch order i,f,g,o — sigm: -log2e, tanh: -2log2e
  const float SC[4] = {-1.44269504f, -1.44269504f, -2.88539008f, -1.44269504f};

  // ---- encoder weight fragments (shared by both chains) ----
  short8 Bh[4][2], Bx[4];
  float bias[4];
  #pragma unroll
  for (int i = 0; i < 4; ++i) {
    const int r = 64*i + j;
    const float s = SC[i];
    #pragma unroll
    for (int f = 0; f < 2; ++f) {
      S8U v;
      #pragma unroll
      for (int e2 = 0; e2 < 4; ++e2)
        v.u[e2] = cvt_pk_bf16(Whh_e[r*HID + f*32 + lg*8 + 2*e2]*s,
                              Whh_e[r*HID + f*32 + lg*8 + 2*e2 + 1]*s);
      Bh[i][f] = v.s;
    }
    S8U vx;
    #pragma unroll
    for (int e2 = 0; e2 < 4; ++e2) {
      const int k0 = lg*8 + 2*e2, k1 = k0 + 1;
      vx.u[e2] = cvt_pk_bf16(k0 < ISZ ? Wih_e[r*ISZ + k0]*s : 0.f,
                             k1 < ISZ ? Wih_e[r*ISZ + k1]*s : 0.f);
    }
    Bx[i] = vx.s;
    bias[i] = b_e[r]*s;
  }

  // ---- per-chain x pipelines: ax[s]=x(t) packed; xf[s]=x(t+2) f32 ----
  const float* xrP = x + (size_t)(b0P + (lc&3))*ISZ;
  const float* xrQ = x + (size_t)(b0Q + (lc&3))*ISZ;
  S8U axP[2], axQ[2];
  float xfP[2][8], xfQ[2][8];
  #pragma unroll
  for (int s = 0; s < 2; ++s) {
    float tp[8], tq[8];
    #pragma unroll
    for (int e = 0; e < 8; ++e) {
      const int k = lg*8 + e;
      tp[e] = (k < ISZ) ? xrP[(size_t)s*BATCH*ISZ + k] : 0.f;
      tq[e] = (k < ISZ) ? xrQ[(size_t)s*BATCH*ISZ + k] : 0.f;
      xfP[s][e] = 0.f; xfQ[s][e] = 0.f;
    }
    #pragma unroll
    for (int e2 = 0; e2 < 4; ++e2) {
      axP[s].u[e2] = cvt_pk_bf16(tp[2*e2], tp[2*e2+1]);
      axQ[s].u[e2] = cvt_pk_bf16(tq[2*e2], tq[2*e2+1]);
    }
  }
  #pragma unroll
  for (int s = 0; s < 2; ++s)
    #pragma unroll
    for (int e = 0; e < 8; ++e) {
      const int k = lg*8 + e;
      if (k < ISZ) { xfP[s][e] = xrP[(size_t)(2+s)*BATCH*ISZ + k];
                     xfQ[s][e] = xrQ[(size_t)(2+s)*BATCH*ISZ + k]; }
    }

  float cP = 0.f, cQ = 0.f;
  f32x4 accxP[4], accxQ[4], gaccP[4], gaccQ[4];

#define REDIST(GACC, W) do { \
    _Pragma("unroll") \
    for (int i_ = 0; i_ < 4; ++i_) { \
      float r0 = GACC[i_][0], r1 = GACC[i_][1], r2 = GACC[i_][2], r3 = GACC[i_][3]; \
      plswap16(r0, r1); \
      plswap16(r2, r3); \
      plswap32(r0, r2); \
      W[i_] = r0; \
    } \
  } while (0)

#define CELL1(W, C, HV) do { \
    const float iv_ = sigm_z(W[0]); \
    const float fv_ = sigm_z(W[1]); \
    const float gv_ = 2.f*sigm_z(W[2]) - 1.f; \
    const float ov_ = sigm_z(W[3]); \
    C = fv_*C + iv_*gv_; \
    const float th_ = 2.f*sigm_z(C * -2.88539008f) - 1.f; \
    HV = ov_*th_; \
  } while (0)

  __syncthreads();   // zero-init visible (one-time full drain ok)

  // prologue: accxP(0) = bias + x_P(0); refill axP[0]<-x2, load xfP[0]<-x4
  #pragma unroll
  for (int i = 0; i < 4; ++i) {
    f32x4 a = {bias[i], bias[i], bias[i], bias[i]};
    accxP[i] = __builtin_amdgcn_mfma_f32_16x16x32_bf16(axP[0].s, Bx[i], a, 0, 0, 0);
  }
  {
    S8U apn;
    #pragma unroll
    for (int e2 = 0; e2 < 4; ++e2) apn.u[e2] = cvt_pk_bf16(xfP[0][2*e2], xfP[0][2*e2+1]);
    axP[0] = apn;
    #pragma unroll
    for (int e = 0; e < 8; ++e) {
      const int k = lg*8 + e;
      if (k < ISZ) xfP[0][e] = xrP[(size_t)4*BATCH*ISZ + k];
    }
  }
  const float* xnP = xrP + (size_t)5*BATCH*ISZ;   // phase2(t) loads x(t+5)
  const float* xnQ = xrQ + (size_t)4*BATCH*ISZ;   // phase1(t) loads x(t+4)

  #pragma unroll 2
  for (int t = 0; t < T_STEPS; ++t) {
    const int s = t & 1;
    // ================= phase 1: P exchange+MFMA  ||  Q cell =================
    short8 ahP0 = *(const short8*)(hP + rof0);
    short8 ahP1 = *(const short8*)(hP + rof1);
    if (t) {
      float wQ[4], hv;
      REDIST(gaccQ, wQ);
      CELL1(wQ, cQ, hv);
      hQ[wof] = (unsigned short)cvt_pk_bf16(hv, hv);   // h_Q(t)
    }
    // accxQ(t) prep + Q x-maintenance (independent of ds_reads)
    #pragma unroll
    for (int i = 0; i < 4; ++i) {
      f32x4 a = {bias[i], bias[i], bias[i], bias[i]};
      accxQ[i] = __builtin_amdgcn_mfma_f32_16x16x32_bf16(axQ[s].s, Bx[i], a, 0, 0, 0);
    }
    {
      S8U aqn;
      #pragma unroll
      for (int e2 = 0; e2 < 4; ++e2) aqn.u[e2] = cvt_pk_bf16(xfQ[s][2*e2], xfQ[s][2*e2+1]);
      axQ[s] = aqn;
      if (t + 4 < T_STEPS) {
        #pragma unroll
        for (int e = 0; e < 8; ++e) { const int k = lg*8 + e; if (k < ISZ) xfQ[s][e] = xnQ[k]; }
      }
      xnQ += BATCH*ISZ;
    }
    asm volatile("s_waitcnt lgkmcnt(0)" ::: "memory");
    #pragma unroll
    for (int i = 0; i < 4; ++i) {
      f32x4 a = __builtin_amdgcn_mfma_f32_16x16x32_bf16(ahP0, Bh[i][0], accxP[i], 0, 0, 0);
      gaccP[i] = __builtin_amdgcn_mfma_f32_16x16x32_bf16(ahP1, Bh[i][1], a, 0, 0, 0);
    }
    lds_barrier();

    // ================= phase 2: Q exchange+MFMA  ||  P cell =================
    short8 ahQ0 = *(const short8*)(hQ + rof0);
    short8 ahQ1 = *(const short8*)(hQ + rof1);
    {
      float wP[4], hv;
      REDIST(gaccP, wP);
      CELL1(wP, cP, hv);
      hP[wof] = (unsigned short)cvt_pk_bf16(hv, hv);   // h_P(t+1)
    }
    // accxP(t+1) prep + P x-maintenance
    #pragma unroll
    for (int i = 0; i < 4; ++i) {
      f32x4 a = {bias[i], bias[i], bias[i], bias[i]};
      accxP[i] = __builtin_amdgcn_mfma_f32_16x16x32_bf16(axP[s^1].s, Bx[i], a, 0, 0, 0);
    }
    {
      S8U apn;
      #pragma unroll
      for (int e2 = 0; e2 < 4; ++e2) apn.u[e2] = cvt_pk_bf16(xfP[s^1][2*e2], xfP[s^1][2*e2+1]);
      axP[s^1] = apn;
      if (t + 5 < T_STEPS) {
        #pragma unroll
        for (int e = 0; e < 8; ++e) { const int k = lg*8 + e; if (k < ISZ) xfP[s^1][e] = xnP[k]; }
      }
      xnP += BATCH*ISZ;
    }
    asm volatile("s_waitcnt lgkmcnt(0)" ::: "memory");
    #pragma unroll
    for (int i = 0; i < 4; ++i) {
      f32x4 a = __builtin_amdgcn_mfma_f32_16x16x32_bf16(ahQ0, Bh[i][0], accxQ[i], 0, 0, 0);
      gaccQ[i] = __builtin_amdgcn_mfma_f32_16x16x32_bf16(ahQ1, Bh[i][1], a, 0, 0, 0);
    }
    lds_barrier();
  }

  // epilogue: cell_Q(255) -> h_Q(final) into buf0
  {
    float wQ[4], hv;
    REDIST(gaccQ, wQ);
    CELL1(wQ, cQ, hv);
    hQ[wof] = (unsigned short)cvt_pk_bf16(hv, hv);
  }

  // ---- decoder weights (prescaled) ----
  #pragma unroll
  for (int i = 0; i < 4; ++i) {
    const int r = 64*i + j;
    const float s = SC[i];
    #pragma unroll
    for (int f = 0; f < 2; ++f) {
      S8U v;
      #pragma unroll
      for (int e2 = 0; e2 < 4; ++e2)
        v.u[e2] = cvt_pk_bf16(Whh_d[r*HID + f*32 + lg*8 + 2*e2]*s,
                              Whh_d[r*HID + f*32 + lg*8 + 2*e2 + 1]*s);
      Bh[i][f] = v.s;
    }
  }
  f32x4 giP[4], giQ[4];
  #pragma unroll
  for (int i = 0; i < 4; ++i) {
    const int r = 64*i + j;
    const float wd = Wih_d[r]*SC[i], bd = b_d[r]*SC[i];
    #pragma unroll
    for (int g = 0; g < 4; ++g) {
      const float yvP = (lg == 0) ? y[b0P + g] : 0.f;
      const float yvQ = (lg == 0) ? y[b0Q + g] : 0.f;
      giP[i][g] = yvP*wd + bd;
      giQ[i][g] = yvQ*wd + bd;
    }
  }
  const float wfc = Wfc[j];
  const float bfv = bfc[0];

  // ---- decoder: h in buf0; 2 barriers/step ----
  for (int p = 0; p < PHOR; ++p) {
    const int pb = p & 1;
    lds_barrier();                       // h(p) (p=0: epilogue write) visible
    const unsigned short* rP = hP + pb*1024;
    const unsigned short* rQ = hQ + pb*1024;
    unsigned short* wPb = hP + (pb^1)*1024;
    unsigned short* wQb = hQ + (pb^1)*1024;
    short8 aP0 = *(const short8*)(rP + rof0);
    short8 aP1 = *(const short8*)(rP + rof1);
    short8 aQ0 = *(const short8*)(rQ + rof0);
    short8 aQ1 = *(const short8*)(rQ + rof1);
    #pragma unroll
    for (int i = 0; i < 4; ++i) {
      f32x4 a = __builtin_amdgcn_mfma_f32_16x16x32_bf16(aP0, Bh[i][0], giP[i], 0, 0, 0);
      gaccP[i] = __builtin_amdgcn_mfma_f32_16x16x32_bf16(aP1, Bh[i][1], a, 0, 0, 0);
      f32x4 b = __builtin_amdgcn_mfma_f32_16x16x32_bf16(aQ0, Bh[i][0], giQ[i], 0, 0, 0);
      gaccQ[i] = __builtin_amdgcn_mfma_f32_16x16x32_bf16(aQ1, Bh[i][1], b, 0, 0, 0);
    }
    float wP[4], wQ[4], hvP, hvQ;
    REDIST(gaccP, wP);
    REDIST(gaccQ, wQ);
    CELL1(wP, cP, hvP);
    CELL1(wQ, cQ, hvQ);
    wPb[wof] = (unsigned short)cvt_pk_bf16(hvP, hvP);
    wQb[wof] = (unsigned short)cvt_pk_bf16(hvQ, hvQ);

    float partP = hvP * wfc, partQ = hvQ * wfc;
    #pragma unroll
    for (int m = 1; m <= 8; m <<= 1) {
      partP += __shfl_xor(partP, m, 64);
      partQ += __shfl_xor(partQ, m, 64);
    }
    if (lc == 0) {
      red[0][pb][wv][lg] = partP;
      red[1][pb][wv][lg] = partQ;
    }
    lds_barrier();                       // red + h(p+1) visible
    if (tid < 2*BPC) {
      const int ch = tid >> 2, b = tid & 3;
      out[(size_t)p*BATCH + b0P + tid] =
          bfv + red[ch][pb][0][b] + red[ch][pb][1][b]
              + red[ch][pb][2][b] + red[ch][pb][3][b];
    }
  }
#undef REDIST
#undef CELL1
}

extern "C" void kernel_launch(void* const* d_in, const int* in_sizes, int n_in,
                              void* d_out, int out_size, void* d_ws, size_t ws_size,
                              hipStream_t stream) {
  const float* x     = (const float*)d_in[0];
  const float* y     = (const float*)d_in[1];
  // d_in[2] = teacher_force (0 in setup; inference branch only)
  const float* Wih_e = (const float*)d_in[3];
  const float* Whh_e = (const float*)d_in[4];
  const float* b_e   = (const float*)d_in[5];
  const float* Wih_d = (const float*)d_in[6];
  const float* Whh_d = (const float*)d_in[7];
  const float* b_d   = (const float*)d_in[8];
  const float* Wfc   = (const float*)d_in[9];
  const float* bfc   = (const float*)d_in[10];
  float* out = (float*)d_out;

  lstm_fused<<<dim3(BATCH/BPB), dim3(256), 0, stream>>>(
      x, y, Wih_e, Whh_e, b_e, Wih_d, Whh_d, b_d, Wfc, bfc, out);
}

// Round 8
// 172.862 us; speedup vs baseline: 1.4880x; 1.4880x over previous
//
#include <hip/hip_runtime.h>
#include <stdint.h>

#define T_STEPS 256
#define BATCH   2048
#define ISZ     11
#define HID     64
#define PHOR    12
#define BPB     8     // batches per block -> 256 blocks = 1 per CU

typedef __attribute__((ext_vector_type(8))) short short8;
typedef __attribute__((ext_vector_type(4))) float f32x4;

union S8U { short8 s; uint32_t u[4]; };

__device__ __forceinline__ uint32_t cvt_pk_bf16(float lo, float hi) {
  uint32_t r;
  asm("v_cvt_pk_bf16_f32 %0, %1, %2" : "=v"(r) : "v"(lo), "v"(hi));
  return r;
}
// sigmoid with pre-scaled input: z = -log2(e)*v  ->  sigm = 1/(1+2^z)
__device__ __forceinline__ float sigm_z(float z) {
  return __builtin_amdgcn_rcpf(1.0f + __builtin_amdgcn_exp2f(z));
}
// D0.hi <-> D1.lo half-wave swap: after call, a[l<32]=a, a[l>=32]=b[l-32].
__device__ __forceinline__ float permswap(float a, float b) {
  asm("v_permlane32_swap_b32 %0, %1" : "+v"(a), "+v"(b));
  return a;
}
// Barrier draining LDS only — global loads stay in flight (no vmcnt(0)).
__device__ __forceinline__ void lds_barrier() {
  asm volatile("s_waitcnt lgkmcnt(0)" ::: "memory");
  __builtin_amdgcn_s_barrier();
  asm volatile("" ::: "memory");
}

// R6 topology (8 batches/block, 256 blocks = 1/CU, 1 barrier/step) with the
// x-MFMA + x-pipeline maintenance moved AFTER the barrier, into the h
// ds_read latency shadow (it is independent of h). Per-step critical path:
// barrier -> max(ds_read, x-work) -> h-MFMA(+add) -> permswap -> cell ->
// write -> barrier.
__global__ __launch_bounds__(256)
void lstm_fused(const float* __restrict__ x, const float* __restrict__ y,
                const float* __restrict__ Wih_e, const float* __restrict__ Whh_e,
                const float* __restrict__ b_e,
                const float* __restrict__ Wih_d, const float* __restrict__ Whh_d,
                const float* __restrict__ b_d,
                const float* __restrict__ Wfc, const float* __restrict__ bfc,
                float* __restrict__ out)
{
  const int tid  = threadIdx.x;
  const int lane = tid & 63;
  const int wv   = tid >> 6;      // 0..3
  const int lc   = lane & 15;     // A-row (batch) / D-col (unit) within tile
  const int lg   = lane >> 4;     // k-group / m-group
  const int b0   = blockIdx.x * BPB;
  const int j    = 16*wv + lc;    // hidden unit this lane owns
  const int bmA  = ((lg & 1) << 2) | (lg & 2);    // 0,4,2,6 per lg
  const int bmB  = bmA + 1;

  // h: [buf][16 rows (8 real)][64 units] bf16, XOR-swizzled 16B granules:
  // elem (b,u) at b*64 + ((u>>3)^(b&7))*8 + (u&7). Rows 8-15 stay zero.
  __shared__ __align__(16) unsigned short hsm[2][16][64];
  __shared__ float red[2][4][BPB];
  unsigned short* hb = &hsm[0][0][0];
  for (int idx = tid; idx < 2*16*64; idx += 256) hb[idx] = 0;

  const int rof0 = lc*64 + ((lg     ^ (lc&7)))*8;  // A-frag units lg*8..+7
  const int rof1 = lc*64 + (((4+lg) ^ (lc&7)))*8;  // units 32+lg*8..+7
  const int wofA = bmA*64 + (((j>>3) ^ (bmA&7))*8) + (j&7);
  const int wofB = bmB*64 + (((j>>3) ^ (bmB&7))*8) + (j&7);

  // gate scales: PyTorch order i,f,g,o — sigm: -log2e, tanh: -2log2e
  const float SC[4] = {-1.44269504f, -1.44269504f, -2.88539008f, -1.44269504f};

  // ---- encoder weight fragments (prescaled, persistent in VGPRs) ----
  short8 Bh[4][2], Bx[4];
  float bias[4];
  #pragma unroll
  for (int i = 0; i < 4; ++i) {
    const int r = 64*i + j;
    const float s = SC[i];
    #pragma unroll
    for (int f = 0; f < 2; ++f) {
      S8U v;
      #pragma unroll
      for (int e2 = 0; e2 < 4; ++e2)
        v.u[e2] = cvt_pk_bf16(Whh_e[r*HID + f*32 + lg*8 + 2*e2]*s,
                              Whh_e[r*HID + f*32 + lg*8 + 2*e2 + 1]*s);
      Bh[i][f] = v.s;
    }
    S8U vx;
    #pragma unroll
    for (int e2 = 0; e2 < 4; ++e2) {
      const int k0 = lg*8 + 2*e2, k1 = k0 + 1;
      vx.u[e2] = cvt_pk_bf16(k0 < ISZ ? Wih_e[r*ISZ + k0]*s : 0.f,
                             k1 < ISZ ? Wih_e[r*ISZ + k1]*s : 0.f);
    }
    Bx[i] = vx.s;
    bias[i] = b_e[r]*s;
  }

  // ---- x pipeline: ax[t&1]=x(t) packed; xf[t&1]=x(t+2) f32 ----
  const float* xrow = x + (size_t)(b0 + (lc & 7))*ISZ;
  float xf[2][8];
  S8U ax[2];
  #pragma unroll
  for (int s = 0; s < 2; ++s) {
    float tmp[8];
    #pragma unroll
    for (int e = 0; e < 8; ++e) {
      const int k = lg*8 + e;
      tmp[e] = (k < ISZ) ? xrow[(size_t)s*BATCH*ISZ + k] : 0.f;
      xf[s][e] = 0.f;
    }
    #pragma unroll
    for (int e2 = 0; e2 < 4; ++e2) ax[s].u[e2] = cvt_pk_bf16(tmp[2*e2], tmp[2*e2+1]);
  }
  #pragma unroll
  for (int s = 0; s < 2; ++s)
    #pragma unroll
    for (int e = 0; e < 8; ++e) {
      const int k = lg*8 + e;
      if (k < ISZ) xf[s][e] = xrow[(size_t)(2+s)*BATCH*ISZ + k];
    }
  const float* xnl = xrow + (size_t)4*BATCH*ISZ;

  float cA = 0.f, cB = 0.f;
  const f32x4 vzero = {0.f, 0.f, 0.f, 0.f};

  // ---- encoder recurrence: barrier at top; x-work in the ds_read shadow ----
  #pragma unroll 2
  for (int t = 0; t < T_STEPS; ++t) {
    const int s = t & 1;
    lds_barrier();                 // h(t) (and first-iter zero-init) visible
    const unsigned short* hr = hb + s*1024;
    unsigned short*       hw = hb + (s^1)*1024;
    short8 ah0 = *(const short8*)(hr + rof0);
    short8 ah1 = *(const short8*)(hr + rof1);

    // ---- ds_read shadow: x-MFMA for THIS step + pipeline maintenance ----
    f32x4 accx[4];
    #pragma unroll
    for (int i = 0; i < 4; ++i) {
      f32x4 a = {bias[i], bias[i], bias[i], bias[i]};
      accx[i] = __builtin_amdgcn_mfma_f32_16x16x32_bf16(ax[s].s, Bx[i], a, 0, 0, 0);
    }
    S8U axn;
    #pragma unroll
    for (int e2 = 0; e2 < 4; ++e2) axn.u[e2] = cvt_pk_bf16(xf[s][2*e2], xf[s][2*e2+1]);
    if (t + 4 < T_STEPS) {
      #pragma unroll
      for (int e = 0; e < 8; ++e) { const int k = lg*8 + e; if (k < ISZ) xf[s][e] = xnl[k]; }
    }
    ax[s] = axn;
    xnl += BATCH*ISZ;

    // ---- h-MFMAs (first use of ds data -> compiler places lgkm wait here) ----
    f32x4 gacc[4];
    #pragma unroll
    for (int i = 0; i < 4; ++i) {
      f32x4 a = __builtin_amdgcn_mfma_f32_16x16x32_bf16(ah0, Bh[i][0], accx[i], 0, 0, 0);
      f32x4 b = __builtin_amdgcn_mfma_f32_16x16x32_bf16(ah1, Bh[i][1], vzero,   0, 0, 0);
      gacc[i] = a + b;
    }

    // redistribute via half-wave swap: every lane gets 2 cell elements
    float gA[4], gB[4];
    #pragma unroll
    for (int i = 0; i < 4; ++i) {
      gA[i] = permswap(gacc[i][0], gacc[i][2]);
      gB[i] = permswap(gacc[i][1], gacc[i][3]);
    }
    const float iA = sigm_z(gA[0]), fA = sigm_z(gA[1]), oA = sigm_z(gA[3]);
    const float iB = sigm_z(gB[0]), fB = sigm_z(gB[1]), oB = sigm_z(gB[3]);
    const float ggA = 2.f*sigm_z(gA[2]) - 1.f;
    const float ggB = 2.f*sigm_z(gB[2]) - 1.f;
    cA = fA*cA + iA*ggA;
    cB = fB*cB + iB*ggB;
    const float thA = 2.f*sigm_z(cA * -2.88539008f) - 1.f;
    const float thB = 2.f*sigm_z(cB * -2.88539008f) - 1.f;
    const float hA = oA*thA, hB = oB*thB;

    const uint32_t pk = cvt_pk_bf16(hA, hB);
    hw[wofA] = (unsigned short)(pk & 0xffffu);
    hw[wofB] = (unsigned short)(pk >> 16);
  }

  // ---- decoder weights (prescaled) ----
  #pragma unroll
  for (int i = 0; i < 4; ++i) {
    const int r = 64*i + j;
    const float s = SC[i];
    #pragma unroll
    for (int f = 0; f < 2; ++f) {
      S8U v;
      #pragma unroll
      for (int e2 = 0; e2 < 4; ++e2)
        v.u[e2] = cvt_pk_bf16(Whh_d[r*HID + f*32 + lg*8 + 2*e2]*s,
                              Whh_d[r*HID + f*32 + lg*8 + 2*e2 + 1]*s);
      Bh[i][f] = v.s;
    }
  }
  f32x4 gi[4];
  {
    float yv[4];
    #pragma unroll
    for (int r = 0; r < 4; ++r) {
      const int m = lg*4 + r;
      yv[r] = (m < BPB) ? y[b0 + m] : 0.f;
    }
    #pragma unroll
    for (int i = 0; i < 4; ++i) {
      const int r = 64*i + j;
      const float wd = Wih_d[r]*SC[i], bd = b_d[r]*SC[i];
      #pragma unroll
      for (int g = 0; g < 4; ++g) gi[i][g] = yv[g]*wd + bd;
    }
  }
  const float wfc = Wfc[j];
  const float bfv = bfc[0];

  // ---- decoder: h(T) sits in buf0 (T even); 2 barriers/step (12 steps) ----
  for (int p = 0; p < PHOR; ++p) {
    const int pb = p & 1;
    lds_barrier();               // h(p) visible
    const unsigned short* hr = hb + pb*1024;
    unsigned short*       hw = hb + (pb^1)*1024;
    short8 ah0 = *(const short8*)(hr + rof0);
    short8 ah1 = *(const short8*)(hr + rof1);
    f32x4 gacc[4];
    #pragma unroll
    for (int i = 0; i < 4; ++i) {
      f32x4 a = __builtin_amdgcn_mfma_f32_16x16x32_bf16(ah0, Bh[i][0], gi[i], 0, 0, 0);
      f32x4 b = __builtin_amdgcn_mfma_f32_16x16x32_bf16(ah1, Bh[i][1], vzero, 0, 0, 0);
      gacc[i] = a + b;
    }
    float gA[4], gB[4];
    #pragma unroll
    for (int i = 0; i < 4; ++i) {
      gA[i] = permswap(gacc[i][0], gacc[i][2]);
      gB[i] = permswap(gacc[i][1], gacc[i][3]);
    }
    const float iA = sigm_z(gA[0]), fA = sigm_z(gA[1]), oA = sigm_z(gA[3]);
    const float iB = sigm_z(gB[0]), fB = sigm_z(gB[1]), oB = sigm_z(gB[3]);
    const float ggA = 2.f*sigm_z(gA[2]) - 1.f;
    const float ggB = 2.f*sigm_z(gB[2]) - 1.f;
    cA = fA*cA + iA*ggA;
    cB = fB*cB + iB*ggB;
    const float thA = 2.f*sigm_z(cA * -2.88539008f) - 1.f;
    const float thB = 2.f*sigm_z(cB * -2.88539008f) - 1.f;
    const float hA = oA*thA, hB = oB*thB;

    const uint32_t pk = cvt_pk_bf16(hA, hB);
    hw[wofA] = (unsigned short)(pk & 0xffffu);
    hw[wofB] = (unsigned short)(pk >> 16);

    float partA = hA * wfc, partB = hB * wfc;
    #pragma unroll
    for (int m = 1; m <= 8; m <<= 1) {
      partA += __shfl_xor(partA, m, 64);
      partB += __shfl_xor(partB, m, 64);
    }
    if (lc == 0) {
      red[pb][wv][bmA] = partA;
      red[pb][wv][bmB] = partB;
    }
    lds_barrier();               // red visible
    if (tid < BPB)
      out[(size_t)p*BATCH + b0 + tid] = bfv + red[pb][0][tid] + red[pb][1][tid]
                                            + red[pb][2][tid] + red[pb][3][tid];
  }
}

extern "C" void kernel_launch(void* const* d_in, const int* in_sizes, int n_in,
                              void* d_out, int out_size, void* d_ws, size_t ws_size,
                              hipStream_t stream) {
  const float* x     = (const float*)d_in[0];
  const float* y     = (const float*)d_in[1];
  // d_in[2] = teacher_force (0 in setup; inference branch only)
  const float* Wih_e = (const float*)d_in[3];
  const float* Whh_e = (const float*)d_in[4];
  const float* b_e   = (const float*)d_in[5];
  const float* Wih_d = (const float*)d_in[6];
  const float* Whh_d = (const float*)d_in[7];
  const float* b_d   = (const float*)d_in[8];
  const float* Wfc   = (const float*)d_in[9];
  const float* bfc   = (const float*)d_in[10];
  float* out = (float*)d_out;

  lstm_fused<<<dim3(BATCH/BPB), dim3(256), 0, stream>>>(
      x, y, Wih_e, Whh_e, b_e, Wih_d, Whh_d, b_d, Wfc, bfc, out);
}